// Round 7
// baseline (8361.710 us; speedup 1.0000x reference)
//
#include <hip/hip_runtime.h>
#include <math.h>

typedef unsigned short u16;
typedef unsigned int   u32;
typedef unsigned long long u64;
typedef _Float16 f16;
typedef __attribute__((ext_vector_type(8))) _Float16 f16x8;
typedef __attribute__((ext_vector_type(4))) float    f32x4;

#define T_SEQ 1024
#define NB    64
#define HID   512
#define KC    384       // 3*128 combined conv+Wx K
#define G4    2048      // 4*HID
#define MR    (NB*T_SEQ) // 65536
#define ZD2   128       // 2*ZD
#define NWG   32        // LSTM workgroups; each owns 16 h-cols

// ---------------- static device buffers ----------------
__device__ __align__(16) f16   g_xwin[(size_t)MR*KC];    // 48 MB window-matrix (f16)
__device__ __align__(16) f16   g_cwxt[(size_t)G4*KC];    // combined (conv_w@Wx)^T  [n][k]
__device__              float  g_bb[G4];                 // conv_b@Wx + b
__device__ __align__(16) f16   g_whT[(size_t)G4*HID];    // Wh^T [2048][512]
__device__ __align__(16) f16   g_w1T[(size_t)HID*HID];
__device__ __align__(16) f16   g_w2T[(size_t)ZD2*HID];
__device__              float  g_b1f[HID];
__device__              float  g_b2f[ZD2];
// XW pre-permuted per-WG: [g][t][b][64 inner], inner = gate*16 + c16 (f16, 256 MB)
__device__ __align__(16) f16   g_xwp[(size_t)NWG*T_SEQ*NB*64];
// h ring: slot t+1 = h_{t+1} row-major [64][512] f16; slot 0 = zeros.
// Doubles as the MLP input (no separate g_hseq).
__device__ __align__(16) f16   g_hstep[(size_t)(T_SEQ+1)*NB*HID];
__device__ __align__(16) f16   g_tmp1[(size_t)MR*HID];   // 64 MB MLP hidden
__device__              int    g_flags[T_SEQ*NWG];
__device__              int    g_in_fp32;

// ---------------- helpers ----------------
__device__ inline float bf2f(u16 u){ union{u32 i; float f;} v; v.i = ((u32)u)<<16; return v.f; }
__device__ inline u16  f2bf(float f){ union{u32 i; float f;} v; v.f = f; u32 u = v.i;
                                      return (u16)((u + 0x7fffu + ((u>>16)&1u))>>16); }
__device__ inline float load_f(const void* p, size_t i, int f32){
  return f32 ? ((const float*)p)[i] : bf2f(((const u16*)p)[i]);
}
__device__ inline float load_in(const void* p, size_t i){ return load_f(p, i, g_in_fp32); }
__device__ inline float xwf(u16 v){ return (float)__builtin_bit_cast(f16, v); }
__device__ inline float fsig(float x){
  return __builtin_amdgcn_rcpf(1.f + __builtin_amdgcn_exp2f(-1.44269504f*x));
}
__device__ inline float ftanh(float x){
  x = fminf(fmaxf(x, -10.f), 10.f);
  float e = __builtin_amdgcn_exp2f(2.88539008f*x);
  return (e - 1.f) * __builtin_amdgcn_rcpf(e + 1.f);
}

// ---------------- dtype probe ----------------
__global__ void k_probe(const void* x){
  __shared__ int cnt;
  if (threadIdx.x == 0) cnt = 0;
  __syncthreads();
  int loc = 0;
  for (int i = threadIdx.x; i < 4096; i += 256){
    float a = fabsf(bf2f(((const u16*)x)[i]));
    if (a > 0.01f && a < 10.f) loc++;
  }
  atomicAdd(&cnt, loc);
  __syncthreads();
  if (threadIdx.x == 0) g_in_fp32 = (cnt < 3276) ? 1 : 0;
}

// ---------------- init: zero flags/h slot0, fp32 biases ----------------
__global__ void k_init(const void* b1, const void* b2){
  int i = blockIdx.x*256 + threadIdx.x;
  if (i < HID)        g_b1f[i] = load_in(b1, i);
  if (i < ZD2)        g_b2f[i] = load_in(b2, i);
  if (i < T_SEQ*NWG)  g_flags[i] = 0;
  if (i < NB*HID/4)   ((u64*)g_hstep)[i] = 0ULL;   // slot 0 = h_0 = zeros (8192 u64)
}

// ---------------- combine conv_w@Wx -> CWx^T, and bb = conv_b@Wx + b ----------------
__global__ void k_combine(const void* conv_w, const void* conv_b, const void* Wx, const void* b){
  int j  = blockIdx.x*256 + threadIdx.x;  // 0..2047
  int kc = blockIdx.y;                    // 0..384 (384 = bias row)
  const int lf = g_in_fp32;
  float acc = 0.f;
  if (kc < KC){
    for (int m = 0; m < HID; ++m)
      acc += load_f(conv_w, (size_t)kc*HID + m, lf) * load_f(Wx, (size_t)m*G4 + j, lf);
    g_cwxt[(size_t)j*KC + kc] = (f16)acc;
  } else {
    for (int m = 0; m < HID; ++m)
      acc += load_f(conv_b, m, lf) * load_f(Wx, (size_t)m*G4 + j, lf);
    g_bb[j] = acc + load_f(b, j, lf);
  }
}

// ---------------- tiled transpose: src [R][C] -> dst [C][R] (f16) ----------------
// NOTE: dst is bound via template/device symbol INSIDE device code — R3-R5
// crashed by passing __device__ symbols as host-side kernel args (host shadow
// address != device address -> wild stores -> HSA fault).
template<int R, int C>
__device__ inline void trans_tile(const void* src, f16* dst){
  __shared__ float tl[32][33];
  const int tx = threadIdx.x & 31, ty = threadIdx.x >> 5;
  const int cb = blockIdx.x*32, rb = blockIdx.y*32;
  const int lf = g_in_fp32;
  #pragma unroll
  for (int yo = 0; yo < 32; yo += 8)
    tl[ty+yo][tx] = load_f(src, (size_t)(rb+ty+yo)*C + cb + tx, lf);
  __syncthreads();
  #pragma unroll
  for (int yo = 0; yo < 32; yo += 8)
    dst[(size_t)(cb+ty+yo)*R + rb + tx] = (f16)tl[tx][ty+yo];
}
__global__ void k_trans_wh(const void* s){ trans_tile<HID, G4 >(s, g_whT); }
__global__ void k_trans_w1(const void* s){ trans_tile<HID, HID>(s, g_w1T); }
__global__ void k_trans_w2(const void* s){ trans_tile<HID, ZD2>(s, g_w2T); }

// ---------------- build sliding-window matrix (SAME pad) ----------------
__global__ void k_xwin(const void* x){
  size_t i = (size_t)blockIdx.x*256 + threadIdx.x;
  if (i >= (size_t)MR*KC) return;
  int row = (int)(i / KC), kc = (int)(i % KC);
  int k = kc >> 7, c = kc & 127;
  int b = row >> 10, t = row & 1023;
  int ts = t - 1 + k;
  float v = 0.f;
  if (ts >= 0 && ts < T_SEQ) v = load_f(x, ((size_t)b*T_SEQ + ts)*128 + c, g_in_fp32);
  g_xwin[i] = (f16)v;
}

// ---------------- generic MFMA f16 GEMM: C = act(A[M,K] @ BT[N,K]^T + bias) ----------------
// MODE 0: permuted f16 store into g_xwp; MODE 1: relu->f16; MODE 2: mu/logsig split.
// AMODE 1: A-row remap into the h ring (row b*T+t -> ring slot t+1, row b).
template<int MODE, int K, int NT, int AMODE>
__device__ inline void gemm_body(const f16* __restrict__ A, const f16* __restrict__ BT,
                                 const float* __restrict__ bias, void* __restrict__ C, int N){
  const int tid = threadIdx.x;
  const int w = tid >> 6, lane = tid & 63;
  const int q = lane >> 4, ln = lane & 15;
  const int n0 = blockIdx.x * (NT*16);
  const int m0 = blockIdx.y * 64;
  const int rm = m0 + w*16 + ln;
  const int ar = (AMODE == 1) ? (((rm & 1023) + 1)*64 + (rm >> 10)) : rm;
  const f16* ap = A + (size_t)ar*K + q*8;
  const f16* bp = BT + (size_t)(n0 + ln)*K + q*8;
  f32x4 acc[NT] = {};
  #pragma unroll 2
  for (int k = 0; k < K; k += 32){
    f16x8 af = *(const f16x8*)(ap + k);
    #pragma unroll
    for (int nt = 0; nt < NT; ++nt){
      f16x8 bf = *(const f16x8*)(bp + (size_t)nt*16*K + k);
      acc[nt] = __builtin_amdgcn_mfma_f32_16x16x32_f16(af, bf, acc[nt], 0, 0, 0);
    }
  }
  const int f32o = g_in_fp32;
  #pragma unroll
  for (int nt = 0; nt < NT; ++nt){
    const int col = n0 + nt*16 + ln;
    const float bv = bias[col];
    #pragma unroll
    for (int r = 0; r < 4; ++r){
      const int row = m0 + w*16 + q*4 + r;
      float v = acc[nt][r] + bv;
      if (MODE == 0){
        int t = row & 1023, b = row >> 10;
        int gw = (col & 511) >> 4, inner = (col >> 9)*16 + (col & 15);
        g_xwp[(((size_t)gw*T_SEQ + t)*NB + b)*64 + inner] = (f16)v;
      } else if (MODE == 1){
        ((f16*)C)[(size_t)row*N + col] = (f16)fmaxf(v, 0.f);
      } else {
        size_t idx = (col < 64) ? ((size_t)row*64 + col)
                                : (4194304UL + (size_t)row*64 + (size_t)(col - 64));
        if (f32o) ((float*)C)[idx] = v;
        else      ((u16*)C)[idx]   = f2bf(v);
      }
    }
  }
}
__global__ __launch_bounds__(256) void k_gemm_xw(){   gemm_body<0,KC, 16,0>(g_xwin,  g_cwxt, g_bb,  nullptr, G4 ); }
__global__ __launch_bounds__(256) void k_gemm_mlp1(){ gemm_body<1,HID,16,1>(g_hstep, g_w1T,  g_b1f, g_tmp1,  HID); }
__global__ __launch_bounds__(256) void k_gemm_mlp2(void* out){ gemm_body<2,HID,8,0>(g_tmp1, g_w2T, g_b2f, out, ZD2); }

// ---------------- persistent LSTM ----------------
// 32 WGs; WG g owns h-cols [16g,16g+16). Gate tiles i/f/g/o = 4 MFMA accumulators
// (no gate shuffles). LDS whs[kq][zrow][8] (kq = kk*4+q): exactly 64 KB,
// quarter-wave reads 16 consecutive 16B chunks. Cross-WG h via u64 agent
// atomics on a fresh per-step ring slot (R2/R6-proven protocol).
__global__ __launch_bounds__(256,1) void k_lstm(){
  __shared__ __align__(16) f16 whs[64*64*8];   // 65,536 B
  const int g   = blockIdx.x;
  const int tid = threadIdx.x;
  const int w = tid >> 6, lane = tid & 63;
  const int q = lane >> 4, ln = lane & 15;

  // stage: whs[(kq*64 + r)*8 + j] = whT[zcol(r)*512 + kq*8 + j]
  for (int idx = tid; idx < 64*64; idx += 256){
    int kq = idx >> 6, r = idx & 63;
    int zcol = (r >> 4)*HID + g*16 + (r & 15);   // zrows 0-15:i, 16-31:f, 32-47:g, 48-63:o
    *(f16x8*)&whs[((size_t)kq*64 + r)*8] = *(const f16x8*)&g_whT[(size_t)zcol*HID + (size_t)kq*8];
  }
  __syncthreads();

  float c_st[4] = {0.f, 0.f, 0.f, 0.f};
  const u16* xwbase = (const u16*)(g_xwp + (size_t)g*T_SEQ*NB*64) + (size_t)(w*16 + q*4)*64 + ln;
  const int am = w*16 + ln;

  for (int t = 0; t < T_SEQ; ++t){
    // XW prefetch: 16 u16 loads from one contiguous 4KB/WG slab — no WG dep,
    // overlaps the flag spin.
    u16 xwv[16];
    {
      const u16* xp = xwbase + (size_t)t*(NB*64);
      #pragma unroll
      for (int kk = 0; kk < 16; ++kk) xwv[kk] = xp[kk*16];
    }
    if (t > 0 && tid < NWG){
      while (__hip_atomic_load(&g_flags[(t-1)*NWG + tid],
                               __ATOMIC_RELAXED, __HIP_MEMORY_SCOPE_AGENT) == 0) {}
    }
    __syncthreads();

    // h_t fragments: 32 pipelined u64 agent-atomic loads (LLC point reads)
    const u64* hrow = (const u64*)(g_hstep + ((size_t)t*NB + am)*HID) + q*2;
    u64 hv[32];
    #pragma unroll
    for (int kk = 0; kk < 16; ++kk){
      hv[2*kk]   = __hip_atomic_load(hrow + (size_t)kk*8,     __ATOMIC_RELAXED, __HIP_MEMORY_SCOPE_AGENT);
      hv[2*kk+1] = __hip_atomic_load(hrow + (size_t)kk*8 + 1, __ATOMIC_RELAXED, __HIP_MEMORY_SCOPE_AGENT);
    }

    f32x4 a0 = {0.f,0.f,0.f,0.f}, a1 = a0, a2 = a0, a3 = a0;
    #pragma unroll
    for (int kk = 0; kk < 16; ++kk){
      union { u64 u[2]; f16x8 v; } cvt;
      cvt.u[0] = hv[2*kk]; cvt.u[1] = hv[2*kk+1];
      const int base = (kk*4 + q)*64*8;
      f16x8 b0 = *(const f16x8*)&whs[base + (  0 + ln)*8];
      f16x8 b1 = *(const f16x8*)&whs[base + ( 16 + ln)*8];
      f16x8 b2 = *(const f16x8*)&whs[base + ( 32 + ln)*8];
      f16x8 b3 = *(const f16x8*)&whs[base + ( 48 + ln)*8];
      a0 = __builtin_amdgcn_mfma_f32_16x16x32_f16(cvt.v, b0, a0, 0, 0, 0);
      a1 = __builtin_amdgcn_mfma_f32_16x16x32_f16(cvt.v, b1, a1, 0, 0, 0);
      a2 = __builtin_amdgcn_mfma_f32_16x16x32_f16(cvt.v, b2, a2, 0, 0, 0);
      a3 = __builtin_amdgcn_mfma_f32_16x16x32_f16(cvt.v, b3, a3, 0, 0, 0);
    }

    #pragma unroll
    for (int r = 0; r < 4; ++r){
      // lane holds z[batch m=w*16+q*4+r][h-col g*16+ln] for each gate
      float zi = a0[r] + xwf(xwv[r*4+0]);
      float zf = a1[r] + xwf(xwv[r*4+1]);
      float zg = a2[r] + xwf(xwv[r*4+2]);
      float zo = a3[r] + xwf(xwv[r*4+3]);
      float iv = fsig(zi), fv = fsig(zf), gv = ftanh(zg), ov = fsig(zo);
      float cn = fv*c_st[r] + iv*gv;
      c_st[r] = cn;
      f16 h16 = (f16)(ov*ftanh(cn));
      // pack 4 cols/u64: lanes ln%4==0 store cols [g*16+ln .. +3] of row m
      u32 me = (u32)__builtin_bit_cast(u16, h16);
      u32 p  = me | (((u32)__shfl_xor((int)me, 1, 64)) << 16);          // even ln
      u64 pk = (u64)p | (((u64)(u32)__shfl_xor((int)p, 2, 64)) << 32);  // ln%4==0
      if ((ln & 3) == 0){
        int m = w*16 + q*4 + r;
        u64* sp = (u64*)(g_hstep + ((size_t)(t+1)*NB + m)*HID + g*16 + ln);
        __hip_atomic_store(sp, pk, __ATOMIC_RELAXED, __HIP_MEMORY_SCOPE_AGENT);
      }
    }
    asm volatile("s_waitcnt vmcnt(0)" ::: "memory");   // drain h stores before flag
    __syncthreads();
    if (tid == 0)
      __hip_atomic_store(&g_flags[t*NWG + g], 1, __ATOMIC_RELAXED, __HIP_MEMORY_SCOPE_AGENT);
  }
}

// ---------------- launch ----------------
extern "C" void kernel_launch(void* const* d_in, const int* in_sizes, int n_in,
                              void* d_out, int out_size, void* d_ws, size_t ws_size,
                              hipStream_t stream){
  const void* x      = d_in[0];
  const void* conv_w = d_in[1];
  const void* conv_b = d_in[2];
  const void* Wx     = d_in[3];
  const void* Wh     = d_in[4];
  const void* b      = d_in[5];
  const void* W1     = d_in[6];
  const void* b1     = d_in[7];
  const void* W2     = d_in[8];
  const void* b2     = d_in[9];
  (void)in_sizes; (void)n_in; (void)out_size; (void)d_ws; (void)ws_size;

  hipLaunchKernelGGL(k_probe,    dim3(1),        dim3(256), 0, stream, x);
  hipLaunchKernelGGL(k_init,     dim3(256),      dim3(256), 0, stream, b1, b2);
  hipLaunchKernelGGL(k_combine,  dim3(8, 385),   dim3(256), 0, stream, conv_w, conv_b, Wx, b);
  hipLaunchKernelGGL(k_trans_wh, dim3(64, 16),   dim3(256), 0, stream, Wh);
  hipLaunchKernelGGL(k_trans_w1, dim3(16, 16),   dim3(256), 0, stream, W1);
  hipLaunchKernelGGL(k_trans_w2, dim3(4, 16),    dim3(256), 0, stream, W2);
  hipLaunchKernelGGL(k_xwin,     dim3(98304),    dim3(256), 0, stream, x);
  hipLaunchKernelGGL(k_gemm_xw,  dim3(8, 1024),  dim3(256), 0, stream);
  hipLaunchKernelGGL(k_lstm,     dim3(NWG),      dim3(256), 0, stream);
  hipLaunchKernelGGL(k_gemm_mlp1, dim3(2, 1024), dim3(256), 0, stream);
  hipLaunchKernelGGL(k_gemm_mlp2, dim3(1, 1024), dim3(256), 0, stream, d_out);
}